// Round 5
// baseline (252.768 us; speedup 1.0000x reference)
//
#include <hip/hip_runtime.h>
#include <stdint.h>

// B=8, S=2048, F=512, D=128, C=1000. I/O fp32; internal bf16 MFMA, fp32 accum.
// mean-attention restructure: w[k] = sum_s exp(S[s,k]-10)/l[s];
// sum_s attn_out = w . V  (V consumed row-major -> no transpose scatter).
// LDS tiles = XOR-swizzled 16B chunks: chunk (r,c) at r*C + (c ^ (r & (C-1))).
// R1: T3 2-phase dbuf prefetch; setprio; wv vectorized bf16x8.
// R3 (failed): cooperative grid.sync not graph-capturable.
// R4 (neutral): P store+reload == recompute cost; ws_size ~256MiB (poison fill).
// R5: register-P fusion with a PLAIN-ATOMIC semaphore barrier (graph-safe).
// grid 512 blocks, __launch_bounds__(256,2): 2 blocks/CU by VGPR cap, 4 by
// LDS -> all 512 co-resident, spin cannot deadlock. exp via single v_exp_f32
// (Q pre-scaled by log2e in qkv epilogue). One fewer kernel, no P traffic.
#define NB 8
#define SS 2048
#define FF 512
#define DD 128
#define CC 1000
#define KC 4              // KV split factor
#define CHUNK (SS / KC)   // 512
#define NBLK (16 * 8 * KC) // 512 blocks in attn_fused

typedef __attribute__((ext_vector_type(8))) short bf16x8;
typedef __attribute__((ext_vector_type(4))) float f32x4;

__device__ __forceinline__ short f2bf(float f) {
    uint32_t u;
    __builtin_memcpy(&u, &f, 4);
    u = (u + 0x7fffu + ((u >> 16) & 1u)) >> 16;   // RNE
    return (short)u;
}
__device__ __forceinline__ float bf2f(short h) {
    uint32_t u = ((uint32_t)(uint16_t)h) << 16;
    float f;
    __builtin_memcpy(&f, &u, 4);
    return f;
}
// 2x f32 -> packed bf16x2 (lo=a, hi=b), single HW instr (T12 recipe)
__device__ __forceinline__ uint32_t cvtpk(float a, float b) {
    uint32_t r;
    asm("v_cvt_pk_bf16_f32 %0, %1, %2" : "=v"(r) : "v"(a), "v"(b));
    return r;
}
// 2^x, single v_exp_f32
__device__ __forceinline__ float exp2_hw(float x) {
    float r;
    asm("v_exp_f32 %0, %1" : "=v"(r) : "v"(x));
    return r;
}
// async 16B global->LDS; LDS dest = wave-uniform base + lane*16
__device__ __forceinline__ void async16(const void* g, void* l) {
    __builtin_amdgcn_global_load_lds(
        (const __attribute__((address_space(1))) uint32_t*)g,
        (__attribute__((address_space(3))) uint32_t*)l, 16, 0, 0);
}

// ---------------------------------------------------------------------------
// Kernel 0 (prep): cast x fp32->bf16 (blocks 0..4095) and transpose+cast the
// projection weights [F][D]f32 -> [D][F]bf16 (blocks 4096..4863).
// ---------------------------------------------------------------------------
__global__ void prep(const float* __restrict__ x,
                     const float* __restrict__ Wq, const float* __restrict__ Wk,
                     const float* __restrict__ Wv,
                     short* __restrict__ xb, short* __restrict__ Wt)
{
    int bx = blockIdx.x;
    if (bx < 4096) {
        int id = bx * 256 + threadIdx.x;
        const float4* src = (const float4*)x + id * 2;
        float4 a = src[0], b2 = src[1];
        bf16x8 o;
        o[0] = f2bf(a.x);  o[1] = f2bf(a.y);  o[2] = f2bf(a.z);  o[3] = f2bf(a.w);
        o[4] = f2bf(b2.x); o[5] = f2bf(b2.y); o[6] = f2bf(b2.z); o[7] = f2bf(b2.w);
        *(bf16x8*)(xb + id * 8) = o;
    } else {
        int id = (bx - 4096) * 256 + threadIdx.x;
        int w = id >> 16, rem = id & 65535;
        int n = rem >> 9, kx = rem & 511;
        const float* Wsrc = (w == 0) ? Wq : (w == 1) ? Wk : Wv;
        Wt[w * 65536 + n * 512 + kx] = f2bf(Wsrc[kx * 128 + n]);
    }
}

// ---------------------------------------------------------------------------
// Kernel 1: fused QKV projection via swizzled global_load_lds.
// C[16384x128] = xb[16384x512] @ Wt^T + bias. grid (128 m-tiles, 3 mats).
// Q output (mat==0) is pre-scaled by log2(e) so attn exp = single v_exp_f32.
// Also zero-inits the attn semaphore (ws is poisoned between iterations).
// ---------------------------------------------------------------------------
__global__ __launch_bounds__(256) void qkv_proj(
    const short* __restrict__ xb, const short* __restrict__ Wt,
    const float* __restrict__ bq, const float* __restrict__ bk, const float* __restrict__ bv,
    short* __restrict__ qo, short* __restrict__ ko, short* __restrict__ vo,
    unsigned int* __restrict__ sem)
{
    __shared__ __align__(16) short As[2][128 * 64];   // swizzled chunks, C=8
    __shared__ __align__(16) short Bs[2][128 * 64];

    const int m0   = blockIdx.x * 128;
    const int mat  = blockIdx.y;
    const int tid  = threadIdx.x;
    const int wave = tid >> 6, lane = tid & 63;
    const int quad = lane >> 4, l16 = lane & 15;
    const int wr = wave >> 1, wc = wave & 1;

    if (mat == 0 && blockIdx.x == 0 && tid == 0) *sem = 0u;

    const short* Wm = Wt + mat * 65536;

    f32x4 acc[4][4];
    for (int i = 0; i < 4; i++)
        for (int j = 0; j < 4; j++) acc[i][j] = (f32x4){0.f, 0.f, 0.f, 0.f};

    const int sr = lane >> 3;
    const int sc = (lane & 7) ^ (sr & 7);

#define QKV_STAGE(buf, kk)                                                  \
    for (int i = 0; i < 4; i++) {                                           \
        int ins = wave * 4 + i;                                             \
        int r = ins * 8 + sr;                                               \
        async16(xb + (m0 + r) * 512 + (kk) + sc * 8, &As[buf][ins * 512]);  \
        async16(Wm + r * 512 + (kk) + sc * 8,        &Bs[buf][ins * 512]);  \
    }

    QKV_STAGE(0, 0)
    __syncthreads();                               // vmcnt drained -> buf0 ready

    int cur = 0;
    for (int t = 0; t < 8; t++) {
        if (t < 7) { QKV_STAGE(cur ^ 1, (t + 1) * 64) }   // prefetch next tile

        for (int kc = 0; kc < 2; kc++) {
            bf16x8 af[4], bfr[4];
            for (int mt = 0; mt < 4; mt++) {
                int R = wr * 64 + mt * 16 + l16, cc = kc * 4 + quad;
                af[mt] = *(const bf16x8*)&As[cur][(R * 8 + (cc ^ (R & 7))) * 8];
            }
            for (int nt = 0; nt < 4; nt++) {
                int R = wc * 64 + nt * 16 + l16, cc = kc * 4 + quad;
                bfr[nt] = *(const bf16x8*)&Bs[cur][(R * 8 + (cc ^ (R & 7))) * 8];
            }
            for (int mt = 0; mt < 4; mt++)
                for (int nt = 0; nt < 4; nt++)
                    acc[mt][nt] = __builtin_amdgcn_mfma_f32_16x16x32_bf16(
                        af[mt], bfr[nt], acc[mt][nt], 0, 0, 0);
        }
        __syncthreads();                           // prefetch drained + reads done
        cur ^= 1;
    }
#undef QKV_STAGE

    const float* bias = (mat == 0) ? bq : (mat == 1) ? bk : bv;
    short* outp = (mat == 0) ? qo : (mat == 1) ? ko : vo;
    const float scale = (mat == 0) ? 1.44269504f : 1.0f;   // log2(e) folded into Q
    for (int mt = 0; mt < 4; mt++) {
        int grow_base = m0 + wr * 64 + mt * 16 + quad * 4;   // C/D row = quad*4+reg
        for (int nt = 0; nt < 4; nt++) {
            int col = wc * 64 + nt * 16 + l16;               // C/D col = lane&15
            float bb = bias[col];
            for (int r = 0; r < 4; r++)
                outp[(grow_base + r) * 128 + col] = f2bf((acc[mt][nt][r] + bb) * scale);
        }
    }
}

// ---------------------------------------------------------------------------
// Kernel 2 (fused attention): one block per (qt, b, lq). NON-cooperative.
// Phase A: stage K chunk (dbuf), S' = q'.K^T (q' = q*log2e), e = 2^(S'-10*log2e)
// via v_exp_f32; P kept bf16-packed in 128 VGPRs; row-sums -> l_part.
// Barrier: threadfence + release atomicAdd(sem); thread0 acquire-spins to 512.
// All 512 blocks co-resident (2/CU by launch_bounds VGPR cap, 4/CU by LDS).
// Phase B: linv from l_part (agent-scope loads), register colsum -> w_part.
// ---------------------------------------------------------------------------
__global__ __launch_bounds__(256, 2) void attn_fused(
    const short* __restrict__ q, const short* __restrict__ k,
    float* __restrict__ l_part, float* __restrict__ w_part,
    float* __restrict__ accum, unsigned int* __restrict__ sem)
{
    __shared__ __align__(16) short ks[2][64 * 128];   // swizzled, C=16 (32 KB)
    __shared__ float wl[4][512];                      // 8 KB

    const int b  = blockIdx.y;
    const int qt = blockIdx.x;
    const int q0 = qt * 128;
    const int lq = blockIdx.z;
    const int c0 = lq * CHUNK;
    const int tid  = threadIdx.x;
    const int wave = tid >> 6, lane = tid & 63;
    const int quad = lane >> 4, l16 = lane & 15;

    if (qt == 0 && b == 0 && lq == 0) {               // zero accum for wv
        accum[tid] = 0.f; accum[256 + tid] = 0.f;
        accum[512 + tid] = 0.f; accum[768 + tid] = 0.f;
    }

    bf16x8 qf[2][4];
    for (int m = 0; m < 2; m++)
        for (int c = 0; c < 4; c++)
            qf[m][c] = *(const bf16x8*)(q + (b * 2048 + q0 + wave * 32 + m * 16 + l16) * 128
                                          + c * 32 + quad * 8);

    float lsum[2][4] = {{0.f,0.f,0.f,0.f},{0.f,0.f,0.f,0.f}};
    uint32_t P[8][4][4];                              // [t][ct][m*2+pair], bf16x2
    const int krl = lane >> 4;                        // 0..3

#define K_STAGE(buf, s0)                                                     \
    for (int i = 0; i < 4; i++) {                                            \
        int ik = wave * 4 + i;                                               \
        int kr = ik * 4 + krl;                                               \
        int kc8 = (lane & 15) ^ (kr & 15);                                   \
        async16(k + (b * 2048 + (s0) + kr) * 128 + kc8 * 8, &ks[buf][ik * 512]); \
    }

    K_STAGE(0, c0)
    __syncthreads();

#pragma unroll
    for (int t = 0; t < 8; t++) {                     // 8 x 64 kv = CHUNK
        if (t < 7) { K_STAGE((t + 1) & 1, c0 + (t + 1) * 64) }

#pragma unroll
        for (int ct = 0; ct < 4; ct++) {
            f32x4 Sf[2];
            Sf[0] = (f32x4){0.f,0.f,0.f,0.f};
            Sf[1] = (f32x4){0.f,0.f,0.f,0.f};
            int R = ct * 16 + l16;                    // R&15 == l16
            __builtin_amdgcn_s_setprio(1);
#pragma unroll
            for (int c = 0; c < 4; c++) {
                int cc = c * 4 + quad;
                bf16x8 kb = *(const bf16x8*)&ks[t & 1][(R * 16 + (cc ^ l16)) * 8];
                for (int m = 0; m < 2; m++)
                    Sf[m] = __builtin_amdgcn_mfma_f32_16x16x32_bf16(
                        qf[m][c], kb, Sf[m], 0, 0, 0);
            }
            __builtin_amdgcn_s_setprio(0);
            float e[2][4];
#pragma unroll
            for (int m = 0; m < 2; m++)
#pragma unroll
                for (int r = 0; r < 4; r++) {
                    // exp(S-10) = 2^(S*log2e - 10*log2e); q pre-scaled by log2e
                    e[m][r] = exp2_hw(Sf[m][r] - 14.4269504f);
                    lsum[m][r] += e[m][r];
                }
#pragma unroll
            for (int m = 0; m < 2; m++) {
                P[t][ct][m * 2 + 0] = cvtpk(e[m][0], e[m][1]);
                P[t][ct][m * 2 + 1] = cvtpk(e[m][2], e[m][3]);
            }
        }
        __syncthreads();
    }
#undef K_STAGE

    // l_part[lq][b][row] = per-chunk row sums
#pragma unroll
    for (int m = 0; m < 2; m++)
#pragma unroll
        for (int r = 0; r < 4; r++) {
            float lv = lsum[m][r];
            lv += __shfl_xor(lv, 1);
            lv += __shfl_xor(lv, 2);
            lv += __shfl_xor(lv, 4);
            lv += __shfl_xor(lv, 8);
            if (l16 == 0)
                l_part[(lq * 8 + b) * 2048 + q0 + wave * 32 + m * 16 + quad * 4 + r] = lv;
        }

    // ---- device-wide barrier via semaphore (all 512 blocks co-resident) ----
    __threadfence();
    __syncthreads();                                  // all waves' stores done
    if (tid == 0) {
        __hip_atomic_fetch_add(sem, 1u, __ATOMIC_RELEASE, __HIP_MEMORY_SCOPE_AGENT);
        while (__hip_atomic_load(sem, __ATOMIC_ACQUIRE, __HIP_MEMORY_SCOPE_AGENT) < NBLK)
            __builtin_amdgcn_s_sleep(2);
    }
    __syncthreads();                                  // publish to whole block

    // Phase B: linv (agent-scope loads bypass L1), register colsum -> w_part
    float linv[2][4];
#pragma unroll
    for (int m = 0; m < 2; m++)
#pragma unroll
        for (int r = 0; r < 4; r++) {
            int row = q0 + wave * 32 + m * 16 + quad * 4 + r;
            float lt = 0.f;
            for (int kc = 0; kc < KC; kc++)
                lt += __hip_atomic_load(&l_part[(kc * 8 + b) * 2048 + row],
                                        __ATOMIC_RELAXED, __HIP_MEMORY_SCOPE_AGENT);
            linv[m][r] = 1.0f / lt;
        }

#pragma unroll
    for (int t = 0; t < 8; t++)
#pragma unroll
        for (int ct = 0; ct < 4; ct++) {
            float cs = 0.f;
#pragma unroll
            for (int m = 0; m < 2; m++) {
                uint32_t u0 = P[t][ct][m * 2 + 0];
                uint32_t u1 = P[t][ct][m * 2 + 1];
                cs += bf2f((short)(u0 & 0xffff)) * linv[m][0];
                cs += bf2f((short)(u0 >> 16))    * linv[m][1];
                cs += bf2f((short)(u1 & 0xffff)) * linv[m][2];
                cs += bf2f((short)(u1 >> 16))    * linv[m][3];
            }
            cs += __shfl_xor(cs, 16);
            cs += __shfl_xor(cs, 32);
            if (quad == 0) wl[wave][t * 64 + ct * 16 + l16] = cs;
        }

    __syncthreads();
    for (int col = tid; col < 512; col += 256) {
        float s = wl[0][col] + wl[1][col] + wl[2][col] + wl[3][col];
        w_part[(qt * 8 + b) * 2048 + c0 + col] = s;
    }
}

// ---------------------------------------------------------------------------
// Kernel 3 (wv): accum[b][d] += sum_s w[b][s] * V[b][s][d], V row-major.
// Vectorized bf16x8 V loads (16B/lane), 128-row slabs, grid (8,16),
// LDS tree-reduce over 16 s-groups -> 1 atomicAdd per (b,d) per block.
// ---------------------------------------------------------------------------
__global__ __launch_bounds__(256) void wv(
    const float* __restrict__ w_part, const short* __restrict__ vo,
    float* __restrict__ accum)
{
    __shared__ float wsh[128];
    __shared__ float red[16][129];                 // +1 pad: conflict-free reads
    const int b    = blockIdx.x;
    const int slab = blockIdx.y;                   // 16 slabs of 128 rows
    const int tid  = threadIdx.x;

    if (tid < 128) {
        int s = slab * 128 + tid;
        float wsum = 0.f;
        for (int qt = 0; qt < 16; qt++) wsum += w_part[(qt * 8 + b) * 2048 + s];
        wsh[tid] = wsum;
    }
    __syncthreads();

    const int dgrp = tid & 15, sgrp = tid >> 4;
    const int d0 = dgrp * 8;
    float a[8] = {0.f,0.f,0.f,0.f,0.f,0.f,0.f,0.f};
    for (int i = 0; i < 8; i++) {
        int sl = sgrp * 8 + i;
        bf16x8 v = *(const bf16x8*)(vo + (size_t)(b * 2048 + slab * 128 + sl) * 128 + d0);
        float w = wsh[sl];
        for (int j = 0; j < 8; j++) a[j] += w * bf2f(v[j]);
    }
    for (int j = 0; j < 8; j++) red[sgrp][d0 + j] = a[j];
    __syncthreads();

    if (tid < 128) {
        float s = 0.f;
        for (int g = 0; g < 16; g++) s += red[g][tid];
        atomicAdd(&accum[b * 128 + tid], s);
    }
}

// ---------------------------------------------------------------------------
// Kernel 4: out[b][c] = (accum[b][:]/2048) . Wl[:,c] + bl[c], fp32 out.
// ---------------------------------------------------------------------------
__global__ void final_proj(const float* __restrict__ accum, const float* __restrict__ Wl,
                           const float* __restrict__ bl, float* __restrict__ out)
{
    int id = blockIdx.x * 256 + threadIdx.x;
    if (id >= NB * CC) return;
    int b = id / CC, c = id % CC;
    float s = 0.f;
    for (int d = 0; d < 128; d++)
        s += accum[b * 128 + d] * Wl[d * 1000 + c];
    out[id] = s * (1.0f / 2048.0f) + bl[c];
}

// ---------------------------------------------------------------------------
extern "C" void kernel_launch(void* const* d_in, const int* in_sizes, int n_in,
                              void* d_out, int out_size, void* d_ws, size_t ws_size,
                              hipStream_t stream) {
    const float* x  = (const float*)d_in[0];
    const float* Wq = (const float*)d_in[1];
    const float* bq = (const float*)d_in[2];
    const float* Wk = (const float*)d_in[3];
    const float* bk = (const float*)d_in[4];
    const float* Wv = (const float*)d_in[5];
    const float* bv = (const float*)d_in[6];
    const float* Wl = (const float*)d_in[7];
    const float* bl = (const float*)d_in[8];
    float* out = (float*)d_out;

    char* ws = (char*)d_ws;
    short* qo     = (short*)(ws);                 // 4 MiB
    short* ko     = (short*)(ws + 4194304);       // 4 MiB
    short* vo     = (short*)(ws + 8388608);       // 4 MiB, row-major [b][s][d]
    short* xb     = (short*)(ws + 12582912);      // 16 MiB (prep+qkv only)
    short* Wt     = (short*)(ws + 29360128);      // 384 KiB
    float* l_part = (float*)(ws + 29753344);      // 256 KiB (KC*8*2048 fp32)
    float* w_part = (float*)(ws + 30277632);      // 1 MiB (16*8*2048 fp32)
    float* acc    = (float*)(ws + 31326208);      // 4 KiB
    unsigned int* sem = (unsigned int*)(ws + 31330304);  // 4 B
    // total ~30 MiB of d_ws

    prep<<<4864, 256, 0, stream>>>(x, Wq, Wk, Wv, xb, Wt);
    qkv_proj<<<dim3(128, 3), 256, 0, stream>>>(xb, Wt, bq, bk, bv, qo, ko, vo, sem);
    attn_fused<<<dim3(16, 8, KC), 256, 0, stream>>>(qo, ko, l_part, w_part, acc, sem);
    wv<<<dim3(8, 16), 256, 0, stream>>>(w_part, vo, acc);
    final_proj<<<(NB * CC + 255) / 256, 256, 0, stream>>>(acc, Wl, bl, out);
}

// Round 6
// 215.641 us; speedup vs baseline: 1.1722x; 1.1722x over previous
//
#include <hip/hip_runtime.h>
#include <stdint.h>

// B=8, S=2048, F=512, D=128, C=1000. I/O fp32; internal bf16 MFMA, fp32 accum.
// mean-attention restructure: w[k] = sum_s exp(S[s,k]-10)/l[s];
// sum_s attn_out = w . V  (V consumed row-major -> no transpose scatter).
// LDS tiles = XOR-swizzled 16B chunks: chunk (r,c) at r*C + (c ^ (r & (C-1))).
// R1: T3 2-phase dbuf prefetch; setprio; wv vectorized bf16x8.
// R3 (failed): cooperative grid.sync not graph-capturable.
// R4 (neutral): P store+reload == recompute cost.
// R5 (regressed): single-line semaphore barrier serializes ~100us. Reverted.
// R6: kernel-count/traffic attack. (a) qkv reads x fp32 DIRECTLY, reg-staged
// cvt_pk->bf16 into the same swizzled LDS layout (prep shrinks to tiny
// W-transpose; kills the 96MB x-cast round trip; 3x fp32 re-read is L3-served).
// (b) final_proj merged into wv via last-block-done counter. 5 kernels total.
#define NB 8
#define SS 2048
#define FF 512
#define DD 128
#define CC 1000
#define KC 8              // KV split factor
#define CHUNK (SS / KC)   // 256

typedef __attribute__((ext_vector_type(8))) short bf16x8;
typedef __attribute__((ext_vector_type(4))) float f32x4;
typedef __attribute__((ext_vector_type(4))) unsigned int u32x4;

__device__ __forceinline__ short f2bf(float f) {
    uint32_t u;
    __builtin_memcpy(&u, &f, 4);
    u = (u + 0x7fffu + ((u >> 16) & 1u)) >> 16;   // RNE
    return (short)u;
}
__device__ __forceinline__ float bf2f(short h) {
    uint32_t u = ((uint32_t)(uint16_t)h) << 16;
    float f;
    __builtin_memcpy(&f, &u, 4);
    return f;
}
// 2x f32 -> packed bf16x2 (lo=a, hi=b), single HW instr
__device__ __forceinline__ uint32_t cvtpk(float a, float b) {
    uint32_t r;
    asm("v_cvt_pk_bf16_f32 %0, %1, %2" : "=v"(r) : "v"(a), "v"(b));
    return r;
}
// async 16B global->LDS; LDS dest = wave-uniform base + lane*16
__device__ __forceinline__ void async16(const void* g, void* l) {
    __builtin_amdgcn_global_load_lds(
        (const __attribute__((address_space(1))) uint32_t*)g,
        (__attribute__((address_space(3))) uint32_t*)l, 16, 0, 0);
}

// ---------------------------------------------------------------------------
// Kernel 0 (prep): transpose+cast projection weights [F][D]f32 -> [D][F]bf16.
// Tiny now (x is consumed fp32 directly by qkv). grid = 768 blocks.
// ---------------------------------------------------------------------------
__global__ void prep(const float* __restrict__ Wq, const float* __restrict__ Wk,
                     const float* __restrict__ Wv, short* __restrict__ Wt)
{
    int id = blockIdx.x * 256 + threadIdx.x;      // 0..196607
    int w = id >> 16, rem = id & 65535;
    int n = rem >> 9, kx = rem & 511;
    const float* Wsrc = (w == 0) ? Wq : (w == 1) ? Wk : Wv;
    Wt[w * 65536 + n * 512 + kx] = f2bf(Wsrc[kx * 128 + n]);
}

// ---------------------------------------------------------------------------
// Kernel 1: fused QKV projection. A-tile staged from x fp32 via registers
// (global_load_dwordx4 x2 -> v_cvt_pk_bf16_f32 x4 -> ds_write_b128) into the
// IDENTICAL swizzled LDS layout async16 produced; B-tile via async16 from Wt.
// T14 split: A-loads for t+1 issued before compute(t); A-write after.
// C[16384x128] = bf16(x)[16384x512] @ Wt^T + bias. grid (128 m-tiles, 3 mats).
// ---------------------------------------------------------------------------
__global__ __launch_bounds__(256) void qkv_proj(
    const float* __restrict__ x, const short* __restrict__ Wt,
    const float* __restrict__ bq, const float* __restrict__ bk, const float* __restrict__ bv,
    short* __restrict__ qo, short* __restrict__ ko, short* __restrict__ vo)
{
    __shared__ __align__(16) short As[2][128 * 64];   // swizzled chunks, C=8
    __shared__ __align__(16) short Bs[2][128 * 64];

    const int m0   = blockIdx.x * 128;
    const int mat  = blockIdx.y;
    const int tid  = threadIdx.x;
    const int wave = tid >> 6, lane = tid & 63;
    const int quad = lane >> 4, l16 = lane & 15;
    const int wr = wave >> 1, wc = wave & 1;

    const short* Wm = Wt + mat * 65536;

    f32x4 acc[4][4];
    for (int i = 0; i < 4; i++)
        for (int j = 0; j < 4; j++) acc[i][j] = (f32x4){0.f, 0.f, 0.f, 0.f};

    const int sr = lane >> 3;
    const int sc = (lane & 7) ^ (sr & 7);

    float4 a0[4], a1[4];                              // in-flight A tile (32 VGPR)

#define A_LOAD(kk)                                                          \
    for (int i = 0; i < 4; i++) {                                           \
        int ins = wave * 4 + i;                                             \
        int r = ins * 8 + sr;                                               \
        const float4* s4 = (const float4*)(x + (size_t)(m0 + r) * 512 + (kk) + sc * 8); \
        a0[i] = s4[0]; a1[i] = s4[1];                                       \
    }
    // chunk (r, sc) lands at short idx ins*512 + lane*8  ==  (r*8 + (sc^(r&7)))*8
#define A_WRITE(buf)                                                        \
    for (int i = 0; i < 4; i++) {                                           \
        int ins = wave * 4 + i;                                             \
        u32x4 p;                                                            \
        p[0] = cvtpk(a0[i].x, a0[i].y);                                     \
        p[1] = cvtpk(a0[i].z, a0[i].w);                                     \
        p[2] = cvtpk(a1[i].x, a1[i].y);                                     \
        p[3] = cvtpk(a1[i].z, a1[i].w);                                     \
        *(u32x4*)&As[buf][ins * 512 + lane * 8] = p;                        \
    }
#define B_STAGE(buf, kk)                                                    \
    for (int i = 0; i < 4; i++) {                                           \
        int ins = wave * 4 + i;                                             \
        int r = ins * 8 + sr;                                               \
        async16(Wm + r * 512 + (kk) + sc * 8, &Bs[buf][ins * 512]);         \
    }

    A_LOAD(0)
    B_STAGE(0, 0)
    A_WRITE(0)
    __syncthreads();                               // drains lgkm + vmcnt -> buf0 ready

    int cur = 0;
    for (int t = 0; t < 8; t++) {
        if (t < 7) {
            A_LOAD((t + 1) * 64)                   // issue loads early (T14)
            B_STAGE(cur ^ 1, (t + 1) * 64)
        }

        for (int kc = 0; kc < 2; kc++) {
            bf16x8 af[4], bfr[4];
            for (int mt = 0; mt < 4; mt++) {
                int R = wr * 64 + mt * 16 + l16, cc = kc * 4 + quad;
                af[mt] = *(const bf16x8*)&As[cur][(R * 8 + (cc ^ (R & 7))) * 8];
            }
            for (int nt = 0; nt < 4; nt++) {
                int R = wc * 64 + nt * 16 + l16, cc = kc * 4 + quad;
                bfr[nt] = *(const bf16x8*)&Bs[cur][(R * 8 + (cc ^ (R & 7))) * 8];
            }
            for (int mt = 0; mt < 4; mt++)
                for (int nt = 0; nt < 4; nt++)
                    acc[mt][nt] = __builtin_amdgcn_mfma_f32_16x16x32_bf16(
                        af[mt], bfr[nt], acc[mt][nt], 0, 0, 0);
        }
        if (t < 7) { A_WRITE(cur ^ 1) }            // loads landed under MFMA
        __syncthreads();
        cur ^= 1;
    }
#undef A_LOAD
#undef A_WRITE
#undef B_STAGE

    const float* bias = (mat == 0) ? bq : (mat == 1) ? bk : bv;
    short* outp = (mat == 0) ? qo : (mat == 1) ? ko : vo;
    for (int mt = 0; mt < 4; mt++) {
        int grow_base = m0 + wr * 64 + mt * 16 + quad * 4;   // C/D row = quad*4+reg
        for (int nt = 0; nt < 4; nt++) {
            int col = wc * 64 + nt * 16 + l16;               // C/D col = lane&15
            float bb = bias[col];
            for (int r = 0; r < 4; r++)
                outp[(grow_base + r) * 128 + col] = f2bf(acc[mt][nt][r] + bb);
        }
    }
}

// ---------------------------------------------------------------------------
// Kernel 2 (pass 1): l_part[kc][b][row] = per-chunk row sums of exp(S-10).
// 128 q-rows/block, KV tile 64, double-buffered K + setprio. Block (0,0,0)
// zero-inits accum and the wv done-counter. grid = (16, 8, KC).
// ---------------------------------------------------------------------------
__global__ __launch_bounds__(256) void attn_l(
    const short* __restrict__ q, const short* __restrict__ k,
    float* __restrict__ l_part, float* __restrict__ accum,
    unsigned int* __restrict__ cnt)
{
    __shared__ __align__(16) short ks[2][64 * 128];   // swizzled, C=16

    const int b  = blockIdx.y;
    const int q0 = blockIdx.x * 128;
    const int lq = blockIdx.z;
    const int c0 = lq * CHUNK;
    const int tid  = threadIdx.x;
    const int wave = tid >> 6, lane = tid & 63;
    const int quad = lane >> 4, l16 = lane & 15;

    if (blockIdx.x == 0 && blockIdx.y == 0 && blockIdx.z == 0) {
        accum[tid] = 0.f; accum[256 + tid] = 0.f;
        accum[512 + tid] = 0.f; accum[768 + tid] = 0.f;
        if (tid == 0) *cnt = 0u;
    }

    bf16x8 qf[2][4];
    for (int m = 0; m < 2; m++)
        for (int c = 0; c < 4; c++)
            qf[m][c] = *(const bf16x8*)(q + (b * 2048 + q0 + wave * 32 + m * 16 + l16) * 128
                                          + c * 32 + quad * 8);

    float lsum[2][4] = {{0.f,0.f,0.f,0.f},{0.f,0.f,0.f,0.f}};
    const int krl = lane >> 4;                        // 0..3

#define K_STAGE(buf, s0)                                                     \
    for (int i = 0; i < 4; i++) {                                            \
        int ik = wave * 4 + i;                                               \
        int kr = ik * 4 + krl;                                               \
        int kc8 = (lane & 15) ^ (kr & 15);                                   \
        async16(k + (b * 2048 + (s0) + kr) * 128 + kc8 * 8, &ks[buf][ik * 512]); \
    }

    K_STAGE(0, c0)
    __syncthreads();

    int cur = 0;
    for (int t = 0; t < CHUNK / 64; t++) {
        if (t < CHUNK / 64 - 1) { K_STAGE(cur ^ 1, c0 + (t + 1) * 64) }

        for (int ct = 0; ct < 4; ct++) {
            f32x4 Sf[2];
            Sf[0] = (f32x4){0.f,0.f,0.f,0.f};
            Sf[1] = (f32x4){0.f,0.f,0.f,0.f};
            int R = ct * 16 + l16;                    // R&15 == l16
            __builtin_amdgcn_s_setprio(1);
            for (int c = 0; c < 4; c++) {
                int cc = c * 4 + quad;
                bf16x8 kb = *(const bf16x8*)&ks[cur][(R * 16 + (cc ^ l16)) * 8];
                for (int m = 0; m < 2; m++)
                    Sf[m] = __builtin_amdgcn_mfma_f32_16x16x32_bf16(
                        qf[m][c], kb, Sf[m], 0, 0, 0);
            }
            __builtin_amdgcn_s_setprio(0);
            for (int m = 0; m < 2; m++)
                for (int r = 0; r < 4; r++)
                    lsum[m][r] += __expf(Sf[m][r] - 10.0f);
        }
        __syncthreads();
        cur ^= 1;
    }

    for (int m = 0; m < 2; m++)
        for (int r = 0; r < 4; r++) {
            float lv = lsum[m][r];
            lv += __shfl_xor(lv, 1);
            lv += __shfl_xor(lv, 2);
            lv += __shfl_xor(lv, 4);
            lv += __shfl_xor(lv, 8);
            if (l16 == 0)
                l_part[(lq * 8 + b) * 2048 + q0 + wave * 32 + m * 16 + quad * 4 + r] = lv;
        }
}

// ---------------------------------------------------------------------------
// Kernel 3 (pass 2): w_part[qt][b][k] = sum over this block's 128 q-rows of
// exp(S-10)/l_total[row]. Plain stores -> no atomics. grid = (16, 8, KC).
// ---------------------------------------------------------------------------
__global__ __launch_bounds__(256) void attn_w(
    const short* __restrict__ q, const short* __restrict__ k,
    const float* __restrict__ l_part, float* __restrict__ w_part)
{
    __shared__ __align__(16) short ks[2][64 * 128];   // swizzled, C=16
    __shared__ float wl[4][256];

    const int b  = blockIdx.y;
    const int qt = blockIdx.x;
    const int q0 = qt * 128;
    const int lq = blockIdx.z;
    const int c0 = lq * CHUNK;
    const int tid  = threadIdx.x;
    const int wave = tid >> 6, lane = tid & 63;
    const int quad = lane >> 4, l16 = lane & 15;

    bf16x8 qf[2][4];
    for (int m = 0; m < 2; m++)
        for (int c = 0; c < 4; c++)
            qf[m][c] = *(const bf16x8*)(q + (b * 2048 + q0 + wave * 32 + m * 16 + l16) * 128
                                          + c * 32 + quad * 8);

    float linv[2][4];
    for (int m = 0; m < 2; m++)
        for (int r = 0; r < 4; r++) {
            int row = q0 + wave * 32 + m * 16 + quad * 4 + r;
            float lt = 0.f;
            for (int kc = 0; kc < KC; kc++) lt += l_part[(kc * 8 + b) * 2048 + row];
            linv[m][r] = 1.0f / lt;
        }

    const int krl = lane >> 4;

    K_STAGE(0, c0)
    __syncthreads();

    int cur = 0;
    for (int t = 0; t < CHUNK / 64; t++) {
        if (t < CHUNK / 64 - 1) { K_STAGE(cur ^ 1, c0 + (t + 1) * 64) }
        int s0 = c0 + t * 64;

        for (int ct = 0; ct < 4; ct++) {
            f32x4 Sf[2];
            Sf[0] = (f32x4){0.f,0.f,0.f,0.f};
            Sf[1] = (f32x4){0.f,0.f,0.f,0.f};
            int R = ct * 16 + l16;
            __builtin_amdgcn_s_setprio(1);
            for (int c = 0; c < 4; c++) {
                int cc = c * 4 + quad;
                bf16x8 kb = *(const bf16x8*)&ks[cur][(R * 16 + (cc ^ l16)) * 8];
                for (int m = 0; m < 2; m++)
                    Sf[m] = __builtin_amdgcn_mfma_f32_16x16x32_bf16(
                        qf[m][c], kb, Sf[m], 0, 0, 0);
            }
            __builtin_amdgcn_s_setprio(0);
            float cs = 0.f;
            for (int m = 0; m < 2; m++)
                for (int r = 0; r < 4; r++)
                    cs += __expf(Sf[m][r] - 10.0f) * linv[m][r];
            cs += __shfl_xor(cs, 16);
            cs += __shfl_xor(cs, 32);
            if (quad == 0) wl[wave][(s0 - c0) + ct * 16 + l16] = cs;
        }
        __syncthreads();
        cur ^= 1;
    }
#undef K_STAGE

    {
        float s = wl[0][tid] + wl[1][tid] + wl[2][tid] + wl[3][tid];
        w_part[(qt * 8 + b) * 2048 + c0 + tid] = s;
    }
}

// ---------------------------------------------------------------------------
// Kernel 4 (wv + last-block final): accum[b][d] += sum_s w[b][s]*V[b][s][d].
// Vectorized bf16x8 V loads, grid (8,16). After the atomicAdd, blocks bump a
// done-counter; the 128th block alone runs the final projection:
// out[b][c] = (accum[b][:]/2048).Wl[:,c] + bl[c], staging Wl rows in LDS.
// ---------------------------------------------------------------------------
__global__ __launch_bounds__(256) void wv_final(
    const float* __restrict__ w_part, const short* __restrict__ vo,
    float* __restrict__ accum, const float* __restrict__ Wl,
    const float* __restrict__ bl, float* __restrict__ out,
    unsigned int* __restrict__ cnt)
{
    __shared__ float smem[9024];                   // 36 KB, phase-aliased
    __shared__ unsigned int lastflag;
    float* wsh = smem;                             // [128]
    float (*red)[129] = (float (*)[129])(smem + 128);   // [16][129]
    const int b    = blockIdx.x;
    const int slab = blockIdx.y;                   // 16 slabs of 128 rows
    const int tid  = threadIdx.x;

    if (tid < 128) {
        int s = slab * 128 + tid;
        float wsum = 0.f;
        for (int qt = 0; qt < 16; qt++) wsum += w_part[(qt * 8 + b) * 2048 + s];
        wsh[tid] = wsum;
    }
    __syncthreads();

    const int dgrp = tid & 15, sgrp = tid >> 4;
    const int d0 = dgrp * 8;
    float a[8] = {0.f,0.f,0.f,0.f,0.f,0.f,0.f,0.f};
    for (int i = 0; i < 8; i++) {
        int sl = sgrp * 8 + i;
        bf16x8 v = *(const bf16x8*)(vo + (size_t)(b * 2048 + slab * 128 + sl) * 128 + d0);
        float w = wsh[sl];
        for (int j = 0; j < 8; j++) a[j] += w * bf2f(v[j]);
    }
    for (int j = 0; j < 8; j++) red[sgrp][d0 + j] = a[j];
    __syncthreads();

    if (tid < 128) {
        float s = 0.f;
        for (int g = 0; g < 16; g++) s += red[g][tid];
        atomicAdd(&accum[b * 128 + tid], s);
    }

    // ---- last-block-done: the 128th block runs the final projection ----
    __threadfence();
    __syncthreads();
    if (tid == 0)
        lastflag = (__hip_atomic_fetch_add(cnt, 1u, __ATOMIC_ACQ_REL,
                        __HIP_MEMORY_SCOPE_AGENT) == 127u) ? 1u : 0u;
    __syncthreads();
    if (lastflag == 0u) return;

    float* acc_l = smem;                           // [1024] (aliases wsh/red)
    float* wlb   = smem + 1024;                    // [8000]
    for (int i = tid; i < 1024; i += 256)
        acc_l[i] = __hip_atomic_load(&accum[i], __ATOMIC_RELAXED,
                                     __HIP_MEMORY_SCOPE_AGENT);
    __syncthreads();

    float o[4][8];
    for (int j = 0; j < 4; j++)
        for (int bb = 0; bb < 8; bb++) o[j][bb] = 0.f;

    for (int dc = 0; dc < 128; dc += 8) {
        for (int i = tid; i < 8000; i += 256)
            wlb[i] = Wl[(dc + i / 1000) * 1000 + (i % 1000)];
        __syncthreads();
        for (int j = 0; j < 4; j++) {
            int c = tid + j * 256;
            if (c < 1000)
                for (int dd = 0; dd < 8; dd++) {
                    float wv_ = wlb[dd * 1000 + c];
                    for (int bb = 0; bb < 8; bb++)
                        o[j][bb] += acc_l[bb * 128 + dc + dd] * wv_;
                }
        }
        __syncthreads();
    }

    for (int j = 0; j < 4; j++) {
        int c = tid + j * 256;
        if (c < 1000) {
            float blc = bl[c];
            for (int bb = 0; bb < 8; bb++)
                out[bb * 1000 + c] = o[j][bb] * (1.0f / 2048.0f) + blc;
        }
    }
}

// ---------------------------------------------------------------------------
extern "C" void kernel_launch(void* const* d_in, const int* in_sizes, int n_in,
                              void* d_out, int out_size, void* d_ws, size_t ws_size,
                              hipStream_t stream) {
    const float* x  = (const float*)d_in[0];
    const float* Wq = (const float*)d_in[1];
    const float* bq = (const float*)d_in[2];
    const float* Wk = (const float*)d_in[3];
    const float* bk = (const float*)d_in[4];
    const float* Wv = (const float*)d_in[5];
    const float* bv = (const float*)d_in[6];
    const float* Wl = (const float*)d_in[7];
    const float* bl = (const float*)d_in[8];
    float* out = (float*)d_out;

    char* ws = (char*)d_ws;
    short* qo     = (short*)(ws);                 // 4 MiB
    short* ko     = (short*)(ws + 4194304);       // 4 MiB
    short* vo     = (short*)(ws + 8388608);       // 4 MiB, row-major [b][s][d]
    short* Wt     = (short*)(ws + 12582912);      // 384 KiB
    float* l_part = (float*)(ws + 12976128);      // 512 KiB (KC*8*2048 fp32)
    float* w_part = (float*)(ws + 13500416);      // 1 MiB (16*8*2048 fp32)
    float* acc    = (float*)(ws + 14548992);      // 4 KiB
    unsigned int* cnt = (unsigned int*)(ws + 14553088);  // 4 B
    // total ~14 MiB of d_ws

    prep<<<768, 256, 0, stream>>>(Wq, Wk, Wv, Wt);
    qkv_proj<<<dim3(128, 3), 256, 0, stream>>>(x, Wt, bq, bk, bv, qo, ko, vo);
    attn_l<<<dim3(16, 8, KC), 256, 0, stream>>>(qo, ko, l_part, acc, cnt);
    attn_w<<<dim3(16, 8, KC), 256, 0, stream>>>(qo, ko, l_part, w_part);
    wv_final<<<dim3(8, 16), 256, 0, stream>>>(w_part, vo, acc, Wl, bl, out, cnt);
}

// Round 8
// 146.111 us; speedup vs baseline: 1.7300x; 1.4759x over previous
//
#include <hip/hip_runtime.h>
#include <stdint.h>

// B=8, S=2048, F=512, D=128, C=1000. I/O fp32; internal bf16 MFMA, fp32 accum.
// mean-attention restructure: w[k] = sum_s exp(S[s,k]-10)/l[s];
// sum_s attn_out = w . V  (V consumed row-major -> no transpose scatter).
// LDS tiles = XOR-swizzled 16B chunks: chunk (r,c) at r*C + (c ^ (r & (C-1))).
// R1: T3 2-phase dbuf prefetch; setprio; wv vectorized bf16x8.
// R3 (failed): cooperative grid.sync not graph-capturable.
// R4 (neutral): P store+reload == recompute cost.
// R5 (regressed): semaphore barrier serializes ~100us.
// R6 (regressed): last-block final_proj = 1 block fetching 4MB Wl alone
//   (~95us idle tail). qkv x-direct + tiny prep kept (traffic win).
// R7: revert ONLY the wv/final merge -> standalone wv + final_proj (32 blocks).
// (R8 resubmit: R7 never ran — container infrastructure failure.)
#define NB 8
#define SS 2048
#define FF 512
#define DD 128
#define CC 1000
#define KC 8              // KV split factor
#define CHUNK (SS / KC)   // 256

typedef __attribute__((ext_vector_type(8))) short bf16x8;
typedef __attribute__((ext_vector_type(4))) float f32x4;
typedef __attribute__((ext_vector_type(4))) unsigned int u32x4;

__device__ __forceinline__ short f2bf(float f) {
    uint32_t u;
    __builtin_memcpy(&u, &f, 4);
    u = (u + 0x7fffu + ((u >> 16) & 1u)) >> 16;   // RNE
    return (short)u;
}
__device__ __forceinline__ float bf2f(short h) {
    uint32_t u = ((uint32_t)(uint16_t)h) << 16;
    float f;
    __builtin_memcpy(&f, &u, 4);
    return f;
}
// 2x f32 -> packed bf16x2 (lo=a, hi=b), single HW instr
__device__ __forceinline__ uint32_t cvtpk(float a, float b) {
    uint32_t r;
    asm("v_cvt_pk_bf16_f32 %0, %1, %2" : "=v"(r) : "v"(a), "v"(b));
    return r;
}
// async 16B global->LDS; LDS dest = wave-uniform base + lane*16
__device__ __forceinline__ void async16(const void* g, void* l) {
    __builtin_amdgcn_global_load_lds(
        (const __attribute__((address_space(1))) uint32_t*)g,
        (__attribute__((address_space(3))) uint32_t*)l, 16, 0, 0);
}

// ---------------------------------------------------------------------------
// Kernel 0 (prep): transpose+cast projection weights [F][D]f32 -> [D][F]bf16.
// Tiny (x is consumed fp32 directly by qkv). grid = 768 blocks.
// ---------------------------------------------------------------------------
__global__ void prep(const float* __restrict__ Wq, const float* __restrict__ Wk,
                     const float* __restrict__ Wv, short* __restrict__ Wt)
{
    int id = blockIdx.x * 256 + threadIdx.x;      // 0..196607
    int w = id >> 16, rem = id & 65535;
    int n = rem >> 9, kx = rem & 511;
    const float* Wsrc = (w == 0) ? Wq : (w == 1) ? Wk : Wv;
    Wt[w * 65536 + n * 512 + kx] = f2bf(Wsrc[kx * 128 + n]);
}

// ---------------------------------------------------------------------------
// Kernel 1: fused QKV projection. A-tile staged from x fp32 via registers
// (global_load_dwordx4 x2 -> v_cvt_pk_bf16_f32 x4 -> ds_write_b128) into the
// IDENTICAL swizzled LDS layout async16 produces; B-tile via async16 from Wt.
// T14 split: A-loads for t+1 issued before compute(t); A-write after.
// C[16384x128] = bf16(x)[16384x512] @ Wt^T + bias. grid (128 m-tiles, 3 mats).
// ---------------------------------------------------------------------------
__global__ __launch_bounds__(256) void qkv_proj(
    const float* __restrict__ x, const short* __restrict__ Wt,
    const float* __restrict__ bq, const float* __restrict__ bk, const float* __restrict__ bv,
    short* __restrict__ qo, short* __restrict__ ko, short* __restrict__ vo)
{
    __shared__ __align__(16) short As[2][128 * 64];   // swizzled chunks, C=8
    __shared__ __align__(16) short Bs[2][128 * 64];

    const int m0   = blockIdx.x * 128;
    const int mat  = blockIdx.y;
    const int tid  = threadIdx.x;
    const int wave = tid >> 6, lane = tid & 63;
    const int quad = lane >> 4, l16 = lane & 15;
    const int wr = wave >> 1, wc = wave & 1;

    const short* Wm = Wt + mat * 65536;

    f32x4 acc[4][4];
    for (int i = 0; i < 4; i++)
        for (int j = 0; j < 4; j++) acc[i][j] = (f32x4){0.f, 0.f, 0.f, 0.f};

    const int sr = lane >> 3;
    const int sc = (lane & 7) ^ (sr & 7);

    float4 a0[4], a1[4];                              // in-flight A tile (32 VGPR)

#define A_LOAD(kk)                                                          \
    for (int i = 0; i < 4; i++) {                                           \
        int ins = wave * 4 + i;                                             \
        int r = ins * 8 + sr;                                               \
        const float4* s4 = (const float4*)(x + (size_t)(m0 + r) * 512 + (kk) + sc * 8); \
        a0[i] = s4[0]; a1[i] = s4[1];                                       \
    }
    // chunk (r, sc) lands at short idx ins*512 + lane*8  ==  (r*8 + (sc^(r&7)))*8
#define A_WRITE(buf)                                                        \
    for (int i = 0; i < 4; i++) {                                           \
        int ins = wave * 4 + i;                                             \
        u32x4 p;                                                            \
        p[0] = cvtpk(a0[i].x, a0[i].y);                                     \
        p[1] = cvtpk(a0[i].z, a0[i].w);                                     \
        p[2] = cvtpk(a1[i].x, a1[i].y);                                     \
        p[3] = cvtpk(a1[i].z, a1[i].w);                                     \
        *(u32x4*)&As[buf][ins * 512 + lane * 8] = p;                        \
    }
#define B_STAGE(buf, kk)                                                    \
    for (int i = 0; i < 4; i++) {                                           \
        int ins = wave * 4 + i;                                             \
        int r = ins * 8 + sr;                                               \
        async16(Wm + r * 512 + (kk) + sc * 8, &Bs[buf][ins * 512]);         \
    }

    A_LOAD(0)
    B_STAGE(0, 0)
    A_WRITE(0)
    __syncthreads();                               // drains lgkm + vmcnt -> buf0 ready

    int cur = 0;
    for (int t = 0; t < 8; t++) {
        if (t < 7) {
            A_LOAD((t + 1) * 64)                   // issue loads early (T14)
            B_STAGE(cur ^ 1, (t + 1) * 64)
        }

        for (int kc = 0; kc < 2; kc++) {
            bf16x8 af[4], bfr[4];
            for (int mt = 0; mt < 4; mt++) {
                int R = wr * 64 + mt * 16 + l16, cc = kc * 4 + quad;
                af[mt] = *(const bf16x8*)&As[cur][(R * 8 + (cc ^ (R & 7))) * 8];
            }
            for (int nt = 0; nt < 4; nt++) {
                int R = wc * 64 + nt * 16 + l16, cc = kc * 4 + quad;
                bfr[nt] = *(const bf16x8*)&Bs[cur][(R * 8 + (cc ^ (R & 7))) * 8];
            }
            for (int mt = 0; mt < 4; mt++)
                for (int nt = 0; nt < 4; nt++)
                    acc[mt][nt] = __builtin_amdgcn_mfma_f32_16x16x32_bf16(
                        af[mt], bfr[nt], acc[mt][nt], 0, 0, 0);
        }
        if (t < 7) { A_WRITE(cur ^ 1) }            // loads landed under MFMA
        __syncthreads();
        cur ^= 1;
    }
#undef A_LOAD
#undef A_WRITE
#undef B_STAGE

    const float* bias = (mat == 0) ? bq : (mat == 1) ? bk : bv;
    short* outp = (mat == 0) ? qo : (mat == 1) ? ko : vo;
    for (int mt = 0; mt < 4; mt++) {
        int grow_base = m0 + wr * 64 + mt * 16 + quad * 4;   // C/D row = quad*4+reg
        for (int nt = 0; nt < 4; nt++) {
            int col = wc * 64 + nt * 16 + l16;               // C/D col = lane&15
            float bb = bias[col];
            for (int r = 0; r < 4; r++)
                outp[(grow_base + r) * 128 + col] = f2bf(acc[mt][nt][r] + bb);
        }
    }
}

// ---------------------------------------------------------------------------
// Kernel 2 (pass 1): l_part[kc][b][row] = per-chunk row sums of exp(S-10).
// 128 q-rows/block, KV tile 64, double-buffered K + setprio. Block (0,0,0)
// zero-inits accum. grid = (16, 8, KC).
// ---------------------------------------------------------------------------
__global__ __launch_bounds__(256) void attn_l(
    const short* __restrict__ q, const short* __restrict__ k,
    float* __restrict__ l_part, float* __restrict__ accum)
{
    __shared__ __align__(16) short ks[2][64 * 128];   // swizzled, C=16

    const int b  = blockIdx.y;
    const int q0 = blockIdx.x * 128;
    const int lq = blockIdx.z;
    const int c0 = lq * CHUNK;
    const int tid  = threadIdx.x;
    const int wave = tid >> 6, lane = tid & 63;
    const int quad = lane >> 4, l16 = lane & 15;

    if (blockIdx.x == 0 && blockIdx.y == 0 && blockIdx.z == 0) {
        accum[tid] = 0.f; accum[256 + tid] = 0.f;
        accum[512 + tid] = 0.f; accum[768 + tid] = 0.f;
    }

    bf16x8 qf[2][4];
    for (int m = 0; m < 2; m++)
        for (int c = 0; c < 4; c++)
            qf[m][c] = *(const bf16x8*)(q + (b * 2048 + q0 + wave * 32 + m * 16 + l16) * 128
                                          + c * 32 + quad * 8);

    float lsum[2][4] = {{0.f,0.f,0.f,0.f},{0.f,0.f,0.f,0.f}};
    const int krl = lane >> 4;                        // 0..3

#define K_STAGE(buf, s0)                                                     \
    for (int i = 0; i < 4; i++) {                                            \
        int ik = wave * 4 + i;                                               \
        int kr = ik * 4 + krl;                                               \
        int kc8 = (lane & 15) ^ (kr & 15);                                   \
        async16(k + (b * 2048 + (s0) + kr) * 128 + kc8 * 8, &ks[buf][ik * 512]); \
    }

    K_STAGE(0, c0)
    __syncthreads();

    int cur = 0;
    for (int t = 0; t < CHUNK / 64; t++) {
        if (t < CHUNK / 64 - 1) { K_STAGE(cur ^ 1, c0 + (t + 1) * 64) }

        for (int ct = 0; ct < 4; ct++) {
            f32x4 Sf[2];
            Sf[0] = (f32x4){0.f,0.f,0.f,0.f};
            Sf[1] = (f32x4){0.f,0.f,0.f,0.f};
            int R = ct * 16 + l16;                    // R&15 == l16
            __builtin_amdgcn_s_setprio(1);
            for (int c = 0; c < 4; c++) {
                int cc = c * 4 + quad;
                bf16x8 kb = *(const bf16x8*)&ks[cur][(R * 16 + (cc ^ l16)) * 8];
                for (int m = 0; m < 2; m++)
                    Sf[m] = __builtin_amdgcn_mfma_f32_16x16x32_bf16(
                        qf[m][c], kb, Sf[m], 0, 0, 0);
            }
            __builtin_amdgcn_s_setprio(0);
            for (int m = 0; m < 2; m++)
                for (int r = 0; r < 4; r++)
                    lsum[m][r] += __expf(Sf[m][r] - 10.0f);
        }
        __syncthreads();
        cur ^= 1;
    }

    for (int m = 0; m < 2; m++)
        for (int r = 0; r < 4; r++) {
            float lv = lsum[m][r];
            lv += __shfl_xor(lv, 1);
            lv += __shfl_xor(lv, 2);
            lv += __shfl_xor(lv, 4);
            lv += __shfl_xor(lv, 8);
            if (l16 == 0)
                l_part[(lq * 8 + b) * 2048 + q0 + wave * 32 + m * 16 + quad * 4 + r] = lv;
        }
}

// ---------------------------------------------------------------------------
// Kernel 3 (pass 2): w_part[qt][b][k] = sum over this block's 128 q-rows of
// exp(S-10)/l_total[row]. Plain stores -> no atomics. grid = (16, 8, KC).
// ---------------------------------------------------------------------------
__global__ __launch_bounds__(256) void attn_w(
    const short* __restrict__ q, const short* __restrict__ k,
    const float* __restrict__ l_part, float* __restrict__ w_part)
{
    __shared__ __align__(16) short ks[2][64 * 128];   // swizzled, C=16
    __shared__ float wl[4][256];

    const int b  = blockIdx.y;
    const int qt = blockIdx.x;
    const int q0 = qt * 128;
    const int lq = blockIdx.z;
    const int c0 = lq * CHUNK;
    const int tid  = threadIdx.x;
    const int wave = tid >> 6, lane = tid & 63;
    const int quad = lane >> 4, l16 = lane & 15;

    bf16x8 qf[2][4];
    for (int m = 0; m < 2; m++)
        for (int c = 0; c < 4; c++)
            qf[m][c] = *(const bf16x8*)(q + (b * 2048 + q0 + wave * 32 + m * 16 + l16) * 128
                                          + c * 32 + quad * 8);

    float linv[2][4];
    for (int m = 0; m < 2; m++)
        for (int r = 0; r < 4; r++) {
            int row = q0 + wave * 32 + m * 16 + quad * 4 + r;
            float lt = 0.f;
            for (int kc = 0; kc < KC; kc++) lt += l_part[(kc * 8 + b) * 2048 + row];
            linv[m][r] = 1.0f / lt;
        }

    const int krl = lane >> 4;

    K_STAGE(0, c0)
    __syncthreads();

    int cur = 0;
    for (int t = 0; t < CHUNK / 64; t++) {
        if (t < CHUNK / 64 - 1) { K_STAGE(cur ^ 1, c0 + (t + 1) * 64) }
        int s0 = c0 + t * 64;

        for (int ct = 0; ct < 4; ct++) {
            f32x4 Sf[2];
            Sf[0] = (f32x4){0.f,0.f,0.f,0.f};
            Sf[1] = (f32x4){0.f,0.f,0.f,0.f};
            int R = ct * 16 + l16;
            __builtin_amdgcn_s_setprio(1);
            for (int c = 0; c < 4; c++) {
                int cc = c * 4 + quad;
                bf16x8 kb = *(const bf16x8*)&ks[cur][(R * 16 + (cc ^ l16)) * 8];
                for (int m = 0; m < 2; m++)
                    Sf[m] = __builtin_amdgcn_mfma_f32_16x16x32_bf16(
                        qf[m][c], kb, Sf[m], 0, 0, 0);
            }
            __builtin_amdgcn_s_setprio(0);
            float cs = 0.f;
            for (int m = 0; m < 2; m++)
                for (int r = 0; r < 4; r++)
                    cs += __expf(Sf[m][r] - 10.0f) * linv[m][r];
            cs += __shfl_xor(cs, 16);
            cs += __shfl_xor(cs, 32);
            if (quad == 0) wl[wave][(s0 - c0) + ct * 16 + l16] = cs;
        }
        __syncthreads();
        cur ^= 1;
    }
#undef K_STAGE

    {
        float s = wl[0][tid] + wl[1][tid] + wl[2][tid] + wl[3][tid];
        w_part[(qt * 8 + b) * 2048 + c0 + tid] = s;
    }
}

// ---------------------------------------------------------------------------
// Kernel 4 (wv): accum[b][d] += sum_s w[b][s] * V[b][s][d], V row-major.
// Vectorized bf16x8 V loads (16B/lane), 128-row slabs, grid (8,16),
// LDS tree-reduce over 16 s-groups -> 1 atomicAdd per (b,d) per block.
// ---------------------------------------------------------------------------
__global__ __launch_bounds__(256) void wv(
    const float* __restrict__ w_part, const short* __restrict__ vo,
    float* __restrict__ accum)
{
    __shared__ float wsh[128];
    __shared__ float red[16][129];                 // +1 pad: conflict-free reads
    const int b    = blockIdx.x;
    const int slab = blockIdx.y;                   // 16 slabs of 128 rows
    const int tid  = threadIdx.x;

    if (tid < 128) {
        int s = slab * 128 + tid;
        float wsum = 0.f;
        for (int qt = 0; qt < 16; qt++) wsum += w_part[(qt * 8 + b) * 2048 + s];
        wsh[tid] = wsum;
    }
    __syncthreads();

    const int dgrp = tid & 15, sgrp = tid >> 4;
    const int d0 = dgrp * 8;
    float a[8] = {0.f,0.f,0.f,0.f,0.f,0.f,0.f,0.f};
    for (int i = 0; i < 8; i++) {
        int sl = sgrp * 8 + i;
        bf16x8 v = *(const bf16x8*)(vo + (size_t)(b * 2048 + slab * 128 + sl) * 128 + d0);
        float w = wsh[sl];
        for (int j = 0; j < 8; j++) a[j] += w * bf2f(v[j]);
    }
    for (int j = 0; j < 8; j++) red[sgrp][d0 + j] = a[j];
    __syncthreads();

    if (tid < 128) {
        float s = 0.f;
        for (int g = 0; g < 16; g++) s += red[g][tid];
        atomicAdd(&accum[b * 128 + tid], s);
    }
}

// ---------------------------------------------------------------------------
// Kernel 5: out[b][c] = (accum[b][:]/2048) . Wl[:,c] + bl[c], fp32 out.
// 32 blocks spread the 4MB Wl read across CUs (R6 lesson: never 1 block).
// ---------------------------------------------------------------------------
__global__ void final_proj(const float* __restrict__ accum, const float* __restrict__ Wl,
                           const float* __restrict__ bl, float* __restrict__ out)
{
    int id = blockIdx.x * 256 + threadIdx.x;
    if (id >= NB * CC) return;
    int b = id / CC, c = id % CC;
    float s = 0.f;
    for (int d = 0; d < 128; d++)
        s += accum[b * 128 + d] * Wl[d * 1000 + c];
    out[id] = s * (1.0f / 2048.0f) + bl[c];
}

// ---------------------------------------------------------------------------
extern "C" void kernel_launch(void* const* d_in, const int* in_sizes, int n_in,
                              void* d_out, int out_size, void* d_ws, size_t ws_size,
                              hipStream_t stream) {
    const float* x  = (const float*)d_in[0];
    const float* Wq = (const float*)d_in[1];
    const float* bq = (const float*)d_in[2];
    const float* Wk = (const float*)d_in[3];
    const float* bk = (const float*)d_in[4];
    const float* Wv = (const float*)d_in[5];
    const float* bv = (const float*)d_in[6];
    const float* Wl = (const float*)d_in[7];
    const float* bl = (const float*)d_in[8];
    float* out = (float*)d_out;

    char* ws = (char*)d_ws;
    short* qo     = (short*)(ws);                 // 4 MiB
    short* ko     = (short*)(ws + 4194304);       // 4 MiB
    short* vo     = (short*)(ws + 8388608);       // 4 MiB, row-major [b][s][d]
    short* Wt     = (short*)(ws + 12582912);      // 384 KiB
    float* l_part = (float*)(ws + 12976128);      // 512 KiB (KC*8*2048 fp32)
    float* w_part = (float*)(ws + 13500416);      // 1 MiB (16*8*2048 fp32)
    float* acc    = (float*)(ws + 14548992);      // 4 KiB
    // total ~14 MiB of d_ws

    prep<<<768, 256, 0, stream>>>(Wq, Wk, Wv, Wt);
    qkv_proj<<<dim3(128, 3), 256, 0, stream>>>(x, Wt, bq, bk, bv, qo, ko, vo);
    attn_l<<<dim3(16, 8, KC), 256, 0, stream>>>(qo, ko, l_part, acc);
    attn_w<<<dim3(16, 8, KC), 256, 0, stream>>>(qo, ko, l_part, w_part);
    wv<<<dim3(8, 16), 256, 0, stream>>>(w_part, vo, acc);
    final_proj<<<(NB * CC + 255) / 256, 256, 0, stream>>>(acc, Wl, bl, out);
}